// Round 7
// baseline (155.998 us; speedup 1.0000x reference)
//
#include <hip/hip_runtime.h>
#include <hip/hip_bf16.h>
#include <stdint.h>

#define EMBED 128
#define HID 145
#define HSTR 160            // padded col count per table
#define NTILE 20            // 320 output cols / 16
#define KCH 4               // 128 K / 32
#define ROWB 192            // int8 row: [0:160) permuted bytes, [160:164) f32 scale, pad
#define LDSROW 208          // LDS staging row stride (bank-spread)
#define NBSHIFT 6           // bucket = src >> 6  (64-node window = 12 KB of u rows)
#define OVFB 128            // overflow-sweep blocks

typedef __attribute__((ext_vector_type(8))) short short8;
typedef __attribute__((ext_vector_type(4))) float f32x4;

__device__ __forceinline__ uint16_t f2bf(float f) {
    uint32_t x = __float_as_uint(f);
    x += 0x7FFFu + ((x >> 16) & 1u);          // round-to-nearest-even
    return (uint16_t)(x >> 16);
}
__device__ __forceinline__ short f2bf_cvt(float f) {
    union { __bf16 h; short s; } u_;
    u_.h = (__bf16)f;                          // compiler pairs into v_cvt_pk_bf16_f32
    return u_.s;
}

// ---------------------------------------------------------------------------
// prep_fused: blocks [0,P): bucket-scatter edges into perm (1 atomicAdd each)
//             blocks [P,P+160): pack W1 into bf16 B-fragment order (Wpb)
//             block P+160: fold cancer/b1/causal cols; permuted w2p
//   perm record = (e<<32)|(src<<16)|dst ; slot = bk*CAP + cursor (ovf tail safe)
// ---------------------------------------------------------------------------
__global__ void __launch_bounds__(256)
prep_fused(const float* __restrict__ cancer, const float* __restrict__ W1,
           const float* __restrict__ b1, const float* __restrict__ W2,
           const void* __restrict__ eiv, int E, int P, int CAP, size_t capSlots,
           float* __restrict__ b1p, float* __restrict__ wci,
           float* __restrict__ wcj, float* __restrict__ w2p,
           short* __restrict__ Wpb, int* __restrict__ counts,
           int* __restrict__ ovfc, unsigned long long* __restrict__ perm)
{
    const int t = threadIdx.x;
    const int b = blockIdx.x;
    if (b < P) {
        // int64 indices < 65536 => every odd 32-bit word is zero.
        const uint32_t* pw = (const uint32_t*)eiv;
        const uint32_t odd = pw[1] | pw[3] | pw[5] | pw[7] | pw[9] | pw[11] | pw[13] | pw[15];
        const int is64 = (odd == 0u);
        const int e = b * 256 + t;
        if (e < E) {
            uint32_t src, dst;
            if (is64) {
                const long long* e64 = (const long long*)eiv;
                src = (uint32_t)e64[e]; dst = (uint32_t)e64[(size_t)E + e];
            } else {
                const uint32_t* e32 = (const uint32_t*)eiv;
                src = e32[e];           dst = e32[(size_t)E + e];
            }
            const int bk = (int)(src >> NBSHIFT);
            const int c = atomicAdd(counts + bk * 16, 1);   // 64B-padded counters
            size_t slot;
            if (c < CAP) slot = (size_t)bk * CAP + (size_t)c;
            else         slot = capSlots + (size_t)atomicAdd(ovfc, 1);
            perm[slot] = ((unsigned long long)(unsigned)e << 32)
                       | ((unsigned long long)(src & 0xFFFFu) << 16)
                       | (unsigned long long)(dst & 0xFFFFu);
        }
        return;
    }
    if (b < P + 160) {
        const int idx = (b - P) * 256 + t;            // < 40960
        const int reg  = idx & 7;
        const int lane = (idx >> 3) & 63;
        const int tl   = idx >> 9;                    // 0..79
        const int tt   = tl % NTILE;
        const int kc   = tl / NTILE;
        const int k    = kc * 32 + (lane >> 4) * 8 + reg;
        const int col  = tt * 16 + (lane & 15);
        float val = 0.f;
        if (col < HID)                             val = W1[(size_t)k * HID + col];
        else if (col >= HSTR && col < HSTR + HID)  val = W1[(size_t)(EMBED + k) * HID + (col - HSTR)];
        Wpb[idx] = (short)f2bf(val);
        return;
    }
    // smalls
    if (t < HSTR) {
        float bv = 0.f, a = 0.f, bb = 0.f;
        if (t < HID) {
            float s = b1[t];
            #pragma unroll
            for (int k = 0; k < 32; ++k)
                s = fmaf(cancer[k], W1[(size_t)(2 * EMBED + k) * HID + t], s);
            bv = s;
            a  = W1[(size_t)288 * HID + t] + W1[(size_t)290 * HID + t];  // c_i + diff
            bb = W1[(size_t)289 * HID + t] - W1[(size_t)290 * HID + t];  // c_j - diff
        }
        b1p[t] = bv; wci[t] = a; wcj[t] = bb;
    }
    if (t < ROWB) {
        // permuted W2 by byte position: pos p -> col (p%10)*16 + p/10
        float w2 = 0.f;
        if (t < HSTR) {
            const int col = (t % 10) * 16 + (t / 10);
            if (col < HID) w2 = W2[col];
        }
        w2p[t] = w2;
    }
}

// ---------------------------------------------------------------------------
// proj_mfma: u'[n] = h[n]@A + b1p + causal[n]*wci   (int8 rowscale, ROWB row)
//            v'[n] = h[n]@B        + causal[n]*wcj
// ---------------------------------------------------------------------------
__global__ void __launch_bounds__(256)
proj_mfma(const float* __restrict__ h, const short* __restrict__ Wpb,
          const float* __restrict__ causal, const float* __restrict__ b1p,
          const float* __restrict__ wci, const float* __restrict__ wcj,
          uint8_t* __restrict__ u, uint8_t* __restrict__ v, int nNodes)
{
    __shared__ uint8_t lds[2 * 64 * LDSROW];
    const int t = threadIdx.x;
    const int lane = t & 63;
    const int w = t >> 6;
    const int lane15 = lane & 15, hi = lane >> 4;
    const int n0blk = blockIdx.x * 64;
    const int nbase = n0blk + w * 16;

    int nodeA = nbase + lane15;
    if (nodeA >= nNodes) nodeA = nNodes - 1;
    const float* hrow = h + (size_t)nodeA * EMBED + hi * 8;

    short8 afr[KCH];
    #pragma unroll
    for (int kc = 0; kc < KCH; ++kc) {
        const float4 x = *(const float4*)(hrow + kc * 32);
        const float4 y = *(const float4*)(hrow + kc * 32 + 4);
        short8 a;
        a[0] = f2bf_cvt(x.x); a[1] = f2bf_cvt(x.y);
        a[2] = f2bf_cvt(x.z); a[3] = f2bf_cvt(x.w);
        a[4] = f2bf_cvt(y.x); a[5] = f2bf_cvt(y.y);
        a[6] = f2bf_cvt(y.z); a[7] = f2bf_cvt(y.w);
        afr[kc] = a;
    }

    f32x4 acc[NTILE];
    #pragma unroll
    for (int tt = 0; tt < NTILE; ++tt) acc[tt] = (f32x4){0.f, 0.f, 0.f, 0.f};

    const short8* bp = (const short8*)Wpb;
    #pragma unroll
    for (int kc = 0; kc < KCH; ++kc) {
        #pragma unroll
        for (int tt = 0; tt < NTILE; ++tt) {
            const short8 b = bp[(kc * NTILE + tt) * 64 + lane];
            acc[tt] = __builtin_amdgcn_mfma_f32_16x16x32_bf16(afr[kc], b, acc[tt], 0, 0, 0);
        }
    }

    float cz[4];
    #pragma unroll
    for (int j = 0; j < 4; ++j) {
        const int n = nbase + hi * 4 + j;
        cz[j] = (n < nNodes) ? causal[n] : 0.f;
    }

    // fold bias/causal terms in place
    #pragma unroll
    for (int tt = 0; tt < NTILE; ++tt) {
        const int col = tt * 16 + lane15;
        const bool isU = (tt < 10);
        const int ccol = isU ? col : col - HSTR;
        const float addB = isU ? b1p[ccol] : 0.f;
        const float addC = isU ? wci[ccol] : wcj[ccol];
        #pragma unroll
        for (int j = 0; j < 4; ++j)
            acc[tt][j] = acc[tt][j] + fmaf(cz[j], addC, addB);
    }

    uint8_t* ldsu = lds;
    uint8_t* ldsv = lds + 64 * LDSROW;

    #pragma unroll
    for (int j = 0; j < 4; ++j) {
        // balanced max trees (clang fuses to v_max3_f32)
        float mu = fmaxf(fmaxf(fmaxf(fabsf(acc[0][j]), fabsf(acc[1][j])),
                               fmaxf(fabsf(acc[2][j]), fabsf(acc[3][j]))),
                         fmaxf(fmaxf(fabsf(acc[4][j]), fabsf(acc[5][j])),
                               fmaxf(fmaxf(fabsf(acc[6][j]), fabsf(acc[7][j])),
                                     fmaxf(fabsf(acc[8][j]), fabsf(acc[9][j])))));
        float mv = fmaxf(fmaxf(fmaxf(fabsf(acc[10][j]), fabsf(acc[11][j])),
                               fmaxf(fabsf(acc[12][j]), fabsf(acc[13][j]))),
                         fmaxf(fmaxf(fabsf(acc[14][j]), fabsf(acc[15][j])),
                               fmaxf(fmaxf(fabsf(acc[16][j]), fabsf(acc[17][j])),
                                     fmaxf(fabsf(acc[18][j]), fabsf(acc[19][j])))));
        #pragma unroll
        for (int m = 1; m < 16; m <<= 1) {
            mu = fmaxf(mu, __shfl_xor(mu, m));
            mv = fmaxf(mv, __shfl_xor(mv, m));
        }
        mu = fmaxf(mu, 1e-20f); mv = fmaxf(mv, 1e-20f);
        const float invu = 127.f / mu, su = mu * (1.f / 127.f);
        const float invv = 127.f / mv, sv = mv * (1.f / 127.f);
        const int row = w * 16 + hi * 4 + j;
        if (lane15 == 0) {
            *(float*)(ldsu + row * LDSROW + HSTR) = su;
            *(float*)(ldsv + row * LDSROW + HSTR) = sv;
        }
        uint8_t* lu = ldsu + row * LDSROW + lane15 * 10;
        uint8_t* lv = ldsv + row * LDSROW + lane15 * 10;
        #pragma unroll
        for (int k = 0; k < 5; ++k) {
            const uint32_t q0 = (uint32_t)(acc[2 * k][j]     * invu + 128.5f);
            const uint32_t q1 = (uint32_t)(acc[2 * k + 1][j] * invu + 128.5f);
            *(uint16_t*)(lu + 2 * k) = (uint16_t)(q0 | (q1 << 8));
            const uint32_t p0 = (uint32_t)(acc[10 + 2 * k][j]     * invv + 128.5f);
            const uint32_t p1 = (uint32_t)(acc[10 + 2 * k + 1][j] * invv + 128.5f);
            *(uint16_t*)(lv + 2 * k) = (uint16_t)(p0 | (p1 << 8));
        }
    }
    __syncthreads();

    // block-wide coalesced copy-out: f in [0,768), row=f/12, off=(f%12)*16
    char* ug = (char*)u + (size_t)n0blk * ROWB;
    char* vg = (char*)v + (size_t)n0blk * ROWB;
    if (n0blk + 64 <= nNodes) {
        #pragma unroll
        for (int i = 0; i < 3; ++i) {
            const int f = i * 256 + t;
            const int row = f / 12, off = (f % 12) * 16;
            *(uint4*)(ug + 16 * f) = *(const uint4*)(ldsu + row * LDSROW + off);
            *(uint4*)(vg + 16 * f) = *(const uint4*)(ldsv + row * LDSROW + off);
        }
    } else {
        #pragma unroll
        for (int i = 0; i < 3; ++i) {
            const int f = i * 256 + t;
            const int row = f / 12, off = (f % 12) * 16;
            if (n0blk + row < nNodes) {
                *(uint4*)(ug + 16 * f) = *(const uint4*)(ldsu + row * LDSROW + off);
                *(uint4*)(vg + 16 * f) = *(const uint4*)(ldsv + row * LDSROW + off);
            }
        }
    }
}

// ---------------------------------------------------------------------------
// edge_binned: blocks [0,2*NB): bucket bk=blockIdx/2, half=blockIdx&1 — all
//   edges of a bucket share a 64-node u-window (12 KB -> L1-resident).
//   blocks [2*NB, 2*NB+OVFB): grid-stride over the overflow tail.
//   4 lanes per edge, 16 edges per wave; int8 rows, scale in lane 3.
// ---------------------------------------------------------------------------
__global__ void __launch_bounds__(256)
edge_binned(const unsigned long long* __restrict__ perm,
            const int* __restrict__ counts, const int* __restrict__ ovfc,
            const uint8_t* __restrict__ u, const uint8_t* __restrict__ v,
            const float* __restrict__ w2p, const float* __restrict__ b2,
            float* __restrict__ out, int NB, int CAP, size_t capSlots)
{
    const int t = threadIdx.x;
    const int lane = t & 63;
    const int r = lane & 3;                 // byte-chunk lane within group
    const int grp = lane >> 2;              // 0..15: edge within wave
    const int w = t >> 6;
    const float bias2 = *b2;

    // per-lane permuted W2 slice: 48 floats
    const float4* wq = (const float4*)w2p + r * 12;
    float4 W2r[12];
    #pragma unroll
    for (int i = 0; i < 12; ++i) W2r[i] = wq[i];

    const unsigned long long* pbase;
    int s, hi, stride;
    if ((int)blockIdx.x < 2 * NB) {
        const int bk = blockIdx.x >> 1, half = blockIdx.x & 1;
        const int HC = CAP >> 1;
        const int cnt = min(counts[bk * 16], CAP);
        pbase  = perm + (size_t)bk * CAP;
        s      = half * HC + w * 16 + grp;
        hi     = min(cnt, (half + 1) * HC);
        stride = 64;
    } else {
        const int ob = (int)blockIdx.x - 2 * NB;
        pbase  = perm + capSlots;
        s      = ob * 64 + w * 16 + grp;
        hi     = *ovfc;
        stride = OVFB * 64;
    }

    while (__any(s < hi)) {
        const bool ok = s < hi;
        const unsigned long long pe = ok ? pbase[s] : 0ull;
        const int e       = (int)(pe >> 32);
        const uint32_t src = (uint32_t)((pe >> 16) & 0xFFFFu);
        const uint32_t dst = (uint32_t)(pe & 0xFFFFu);

        const char* ub = (const char*)u + src * (uint32_t)ROWB + r * 48;
        const char* vb = (const char*)v + dst * (uint32_t)ROWB + r * 48;
        uint4 U[3], V[3];
        #pragma unroll
        for (int i = 0; i < 3; ++i) U[i] = *(const uint4*)(ub + 16 * i);
        #pragma unroll
        for (int i = 0; i < 3; ++i) V[i] = *(const uint4*)(vb + 16 * i);

        // scales live at row bytes 160..163 = lane r=3, word U[1].x
        const float su = __shfl(__uint_as_float(U[1].x), lane | 3);
        const float sv = __shfl(__uint_as_float(V[1].x), lane | 3);
        const float off = -128.f * (su + sv);

        float acc = 0.f;
        const float* w2f = (const float*)W2r;
        #pragma unroll
        for (int i = 0; i < 3; ++i) {
            const uint32_t* uw = (const uint32_t*)&U[i];
            const uint32_t* vw = (const uint32_t*)&V[i];
            #pragma unroll
            for (int d = 0; d < 4; ++d) {
                const uint32_t uword = uw[d], vword = vw[d];
                #pragma unroll
                for (int k = 0; k < 4; ++k) {
                    const float uf = (float)((uword >> (8 * k)) & 0xFFu);
                    const float vf = (float)((vword >> (8 * k)) & 0xFFu);
                    float tv = fmaf(su, uf, fmaf(sv, vf, off));
                    tv = fmaxf(tv, 0.f);
                    acc = fmaf(tv, w2f[i * 16 + d * 4 + k], acc);
                }
            }
        }
        float partial = acc;
        partial += __shfl_xor(partial, 1);
        partial += __shfl_xor(partial, 2);
        if (r == 0 && ok)
            out[e] = 1.f / (1.f + __expf(-(partial + bias2)));
        s += stride;
    }
}

// ---------------------------------------------------------------------------
// fallback_kernel: direct per-edge compute (ws too small or nNodes > 65536)
// ---------------------------------------------------------------------------
__global__ void __launch_bounds__(256)
fallback_kernel(const void* __restrict__ eiv, const float* __restrict__ h,
                const float* __restrict__ cancer, const float* __restrict__ causal,
                const float* __restrict__ W1, const float* __restrict__ b1,
                const float* __restrict__ W2, const float* __restrict__ b2,
                float* __restrict__ out, int E)
{
    const int lane = threadIdx.x & 63;
    const int wpb  = blockDim.x >> 6;
    const int wid  = blockIdx.x * wpb + (threadIdx.x >> 6);
    const int nW   = gridDim.x * wpb;
    const uint32_t* p32 = (const uint32_t*)eiv;
    const uint32_t o = p32[1] | p32[3] | p32[5] | p32[7] | p32[9] | p32[11] | p32[13] | p32[15];
    const int is64 = (o == 0u);
    const long long* e64 = (const long long*)eiv;
    const int*       e32 = (const int*)eiv;
    const float bias2 = *b2;

    for (int e = wid; e < E; e += nW) {
        long long src, dst;
        if (is64) { src = e64[e]; dst = e64[(size_t)E + e]; }
        else      { src = e32[e]; dst = e32[(size_t)E + e]; }
        const float ci = causal[src], cj = causal[dst];
        float acc0 = 0.f, acc1 = 0.f, acc2 = 0.f;
        const int j0 = lane, j1 = lane + 64, j2 = lane + 128;
        for (int k = 0; k < 291; ++k) {
            float f;
            if      (k < 128) f = h[(size_t)src * 128 + k];
            else if (k < 256) f = h[(size_t)dst * 128 + (k - 128)];
            else if (k < 288) f = cancer[k - 256];
            else if (k == 288) f = ci;
            else if (k == 289) f = cj;
            else               f = ci - cj;
            const float* wr = W1 + (size_t)k * HID;
            acc0 = fmaf(f, wr[j0], acc0);
            acc1 = fmaf(f, wr[j1], acc1);
            if (j2 < HID) acc2 = fmaf(f, wr[j2], acc2);
        }
        float partial = fmaxf(acc0 + b1[j0], 0.f) * W2[j0]
                      + fmaxf(acc1 + b1[j1], 0.f) * W2[j1];
        if (j2 < HID) partial += fmaxf(acc2 + b1[j2], 0.f) * W2[j2];
        #pragma unroll
        for (int m = 32; m; m >>= 1) partial += __shfl_xor(partial, m, 64);
        if (lane == 0) out[e] = 1.f / (1.f + __expf(-(partial + bias2)));
    }
}

// ---------------------------------------------------------------------------
extern "C" void kernel_launch(void* const* d_in, const int* in_sizes, int n_in,
                              void* d_out, int out_size, void* d_ws, size_t ws_size,
                              hipStream_t stream)
{
    const float* h      = (const float*)d_in[0];
    const void*  ei     = d_in[1];
    const float* cancer = (const float*)d_in[2];
    const float* causal = (const float*)d_in[3];
    const float* W1     = (const float*)d_in[4];
    const float* b1     = (const float*)d_in[5];
    const float* W2     = (const float*)d_in[6];
    const float* b2     = (const float*)d_in[7];
    float* outp = (float*)d_out;

    const int nNodes = in_sizes[0] / EMBED;
    const int E      = in_sizes[1] / 2;

    // bucket geometry
    const int NB  = (nNodes + 63) >> NBSHIFT;                  // <= 1024
    int CAP = (E + NB - 1) / NB;  CAP += CAP >> 1;             // 1.5x avg
    CAP = (CAP + 127) & ~127;
    const size_t capSlots  = (size_t)NB * CAP;
    const size_t permSlots = capSlots + (size_t)E;             // full ovf tail

    // workspace layout
    const size_t WPB_OFF  = 8192;                              // 80 KB -> 90112
    const size_t CNT_OFF  = 90112;                             // 1024*64 B
    const size_t PERM_OFF = 155904;                            // CNT ends 155648, +ovfc pad
    const size_t OVF_OFF  = 155648;
    const size_t permB    = permSlots * 8;
    const size_t tabB     = (size_t)nNodes * ROWB;             // 9.6 MB each
    const size_t U_OFF    = (PERM_OFF + permB + 255) & ~(size_t)255;
    const size_t V_OFF    = (U_OFF + tabB + 255) & ~(size_t)255;
    const size_t need     = V_OFF + tabB;

    char* ws = (char*)d_ws;
    float* b1p  = (float*)(ws + 1024);
    float* wci  = (float*)(ws + 2048);
    float* wcj  = (float*)(ws + 3072);
    float* w2p  = (float*)(ws + 4096);
    short* Wpb  = (short*)(ws + WPB_OFF);

    if (ws_size >= need && nNodes <= 65536) {
        int* counts = (int*)(ws + CNT_OFF);
        int* ovfc   = (int*)(ws + OVF_OFF);
        unsigned long long* perm = (unsigned long long*)(ws + PERM_OFF);
        uint8_t* u = (uint8_t*)(ws + U_OFF);
        uint8_t* v = (uint8_t*)(ws + V_OFF);

        // zero bucket counters + overflow cursor (stream-ordered, capture-safe)
        hipMemsetAsync(ws + CNT_OFF, 0, PERM_OFF - CNT_OFF, stream);

        const int P = (E + 255) / 256;
        prep_fused<<<P + 161, 256, 0, stream>>>(cancer, W1, b1, W2, ei, E, P,
                                                CAP, capSlots,
                                                b1p, wci, wcj, w2p, Wpb,
                                                counts, ovfc, perm);
        proj_mfma<<<(nNodes + 63) / 64, 256, 0, stream>>>(h, Wpb, causal, b1p,
                                                          wci, wcj, u, v, nNodes);
        edge_binned<<<2 * NB + OVFB, 256, 0, stream>>>(perm, counts, ovfc, u, v,
                                                       w2p, b2, outp, NB, CAP,
                                                       capSlots);
    } else {
        fallback_kernel<<<2048, 256, 0, stream>>>(ei, h, cancer, causal, W1, b1, W2, b2,
                                                  outp, E);
    }
}

// Round 9
// 82.014 us; speedup vs baseline: 1.9021x; 1.9021x over previous
//
#include <hip/hip_runtime.h>
#include <hip/hip_bf16.h>
#include <stdint.h>

#define EMBED 128
#define HID 145
#define HSTR 160            // padded col count per table (MFMA tiles)
#define NTILE 20            // 320 output cols / 16
#define KCH 4               // 128 K / 32
#define MROWB 128           // int6 row: 29 u32 packed vals (cols 0..144) + f32 scale @ u32 29
#define LROW 152            // LDS staging row stride: 145 bytes + 3 pad + f32 scale @ 148

typedef __attribute__((ext_vector_type(8))) short short8;
typedef __attribute__((ext_vector_type(4))) float f32x4;

__device__ __forceinline__ uint16_t f2bf(float f) {
    uint32_t x = __float_as_uint(f);
    x += 0x7FFFu + ((x >> 16) & 1u);          // round-to-nearest-even
    return (uint16_t)(x >> 16);
}
__device__ __forceinline__ short f2bf_cvt(float f) {
    union { __bf16 h; short s; } u_;
    u_.h = (__bf16)f;
    return u_.s;
}

// ---------------------------------------------------------------------------
// prep_fused: blocks [0,P): pack pairs[e]=(src<<16)|dst
//             blocks [P,P+160): pack W1 into bf16 B-fragment order (Wpb)
//             block P+160: fold cancer/b1/causal cols; plain zero-padded W2
// ---------------------------------------------------------------------------
__global__ void __launch_bounds__(256)
prep_fused(const float* __restrict__ cancer, const float* __restrict__ W1,
           const float* __restrict__ b1, const float* __restrict__ W2,
           const void* __restrict__ eiv, int E, int P,
           float* __restrict__ b1p, float* __restrict__ wci,
           float* __restrict__ wcj, float* __restrict__ w2p,
           short* __restrict__ Wpb, uint32_t* __restrict__ pairs)
{
    const int t = threadIdx.x;
    const int b = blockIdx.x;
    if (b < P) {
        // int64 indices < 65536 => every odd 32-bit word is zero.
        const uint32_t* pw = (const uint32_t*)eiv;
        const uint32_t odd = pw[1] | pw[3] | pw[5] | pw[7] | pw[9] | pw[11] | pw[13] | pw[15];
        const int is64 = (odd == 0u);
        const int e = b * 256 + t;
        if (e < E) {
            uint32_t src, dst;
            if (is64) {
                const long long* e64 = (const long long*)eiv;
                src = (uint32_t)e64[e]; dst = (uint32_t)e64[(size_t)E + e];
            } else {
                const uint32_t* e32 = (const uint32_t*)eiv;
                src = e32[e];           dst = e32[(size_t)E + e];
            }
            pairs[e] = (src << 16) | (dst & 0xFFFFu);
        }
        return;
    }
    if (b < P + 160) {
        const int idx = (b - P) * 256 + t;            // < 40960
        const int reg  = idx & 7;
        const int lane = (idx >> 3) & 63;
        const int tl   = idx >> 9;                    // 0..79
        const int tt   = tl % NTILE;
        const int kc   = tl / NTILE;
        const int k    = kc * 32 + (lane >> 4) * 8 + reg;
        const int col  = tt * 16 + (lane & 15);
        float val = 0.f;
        if (col < HID)                             val = W1[(size_t)k * HID + col];
        else if (col >= HSTR && col < HSTR + HID)  val = W1[(size_t)(EMBED + k) * HID + (col - HSTR)];
        Wpb[idx] = (short)f2bf(val);
        return;
    }
    // smalls
    if (t < HSTR) {
        float bv = 0.f, a = 0.f, bb = 0.f, w2 = 0.f;
        if (t < HID) {
            float s = b1[t];
            #pragma unroll
            for (int k = 0; k < 32; ++k)
                s = fmaf(cancer[k], W1[(size_t)(2 * EMBED + k) * HID + t], s);
            bv = s;
            a  = W1[(size_t)288 * HID + t] + W1[(size_t)290 * HID + t];  // c_i + diff
            bb = W1[(size_t)289 * HID + t] - W1[(size_t)290 * HID + t];  // c_j - diff
            w2 = W2[t];
        }
        b1p[t] = bv; wci[t] = a; wcj[t] = bb; w2p[t] = w2;   // plain col order
    }
}

// ---------------------------------------------------------------------------
// proj_mfma: u'[n] = h[n]@A + b1p + causal[n]*wci   (int6 rowscale, 128 B row)
//            v'[n] = h[n]@B        + causal[n]*wcj
//   Epilogue: fold -> per-row absmax -> 6-bit biased quantize (q = x*31/max
//   + 32.5, in [1,63]) -> LDS bytes in col order -> repack 5 vals/u32 ->
//   coalesced uint4 copy-out. Scale f32 at u32 index 29 of each row.
//   RACE FIX (r8 post-mortem): only cols 0..144 are staged. tt=0..8 for all
//   lane15; col 144 (tile 9, lane15==0) separately. Bytes 145..147 unwritten
//   (repack uses only byte 144 of that word); scale at 148 no longer
//   clobbered; no spill into the next row's bytes.
// ---------------------------------------------------------------------------
__global__ void __launch_bounds__(256)
proj_mfma(const float* __restrict__ h, const short* __restrict__ Wpb,
          const float* __restrict__ causal, const float* __restrict__ b1p,
          const float* __restrict__ wci, const float* __restrict__ wcj,
          uint8_t* __restrict__ u, uint8_t* __restrict__ v, int nNodes)
{
    __shared__ uint8_t lds[2 * 64 * LROW];
    const int t = threadIdx.x;
    const int lane = t & 63;
    const int w = t >> 6;
    const int lane15 = lane & 15, hi = lane >> 4;
    const int n0blk = blockIdx.x * 64;
    const int nbase = n0blk + w * 16;

    int nodeA = nbase + lane15;
    if (nodeA >= nNodes) nodeA = nNodes - 1;
    const float* hrow = h + (size_t)nodeA * EMBED + hi * 8;

    short8 afr[KCH];
    #pragma unroll
    for (int kc = 0; kc < KCH; ++kc) {
        const float4 x = *(const float4*)(hrow + kc * 32);
        const float4 y = *(const float4*)(hrow + kc * 32 + 4);
        short8 a;
        a[0] = f2bf_cvt(x.x); a[1] = f2bf_cvt(x.y);
        a[2] = f2bf_cvt(x.z); a[3] = f2bf_cvt(x.w);
        a[4] = f2bf_cvt(y.x); a[5] = f2bf_cvt(y.y);
        a[6] = f2bf_cvt(y.z); a[7] = f2bf_cvt(y.w);
        afr[kc] = a;
    }

    f32x4 acc[NTILE];
    #pragma unroll
    for (int tt = 0; tt < NTILE; ++tt) acc[tt] = (f32x4){0.f, 0.f, 0.f, 0.f};

    const short8* bp = (const short8*)Wpb;
    #pragma unroll
    for (int kc = 0; kc < KCH; ++kc) {
        #pragma unroll
        for (int tt = 0; tt < NTILE; ++tt) {
            const short8 b = bp[(kc * NTILE + tt) * 64 + lane];
            acc[tt] = __builtin_amdgcn_mfma_f32_16x16x32_bf16(afr[kc], b, acc[tt], 0, 0, 0);
        }
    }

    float cz[4];
    #pragma unroll
    for (int j = 0; j < 4; ++j) {
        const int n = nbase + hi * 4 + j;
        cz[j] = (n < nNodes) ? causal[n] : 0.f;
    }

    // fold bias/causal terms in place
    #pragma unroll
    for (int tt = 0; tt < NTILE; ++tt) {
        const int col = tt * 16 + lane15;
        const bool isU = (tt < 10);
        const int ccol = isU ? col : col - HSTR;
        const float addB = isU ? b1p[ccol] : 0.f;
        const float addC = isU ? wci[ccol] : wcj[ccol];
        #pragma unroll
        for (int j = 0; j < 4; ++j)
            acc[tt][j] = acc[tt][j] + fmaf(cz[j], addC, addB);
    }

    uint8_t* ldsu = lds;
    uint8_t* ldsv = lds + 64 * LROW;

    #pragma unroll
    for (int j = 0; j < 4; ++j) {
        float mu = fmaxf(fmaxf(fmaxf(fabsf(acc[0][j]), fabsf(acc[1][j])),
                               fmaxf(fabsf(acc[2][j]), fabsf(acc[3][j]))),
                         fmaxf(fmaxf(fabsf(acc[4][j]), fabsf(acc[5][j])),
                               fmaxf(fmaxf(fabsf(acc[6][j]), fabsf(acc[7][j])),
                                     fmaxf(fabsf(acc[8][j]), fabsf(acc[9][j])))));
        float mv = fmaxf(fmaxf(fmaxf(fabsf(acc[10][j]), fabsf(acc[11][j])),
                               fmaxf(fabsf(acc[12][j]), fabsf(acc[13][j]))),
                         fmaxf(fmaxf(fabsf(acc[14][j]), fabsf(acc[15][j])),
                               fmaxf(fmaxf(fabsf(acc[16][j]), fabsf(acc[17][j])),
                                     fmaxf(fabsf(acc[18][j]), fabsf(acc[19][j])))));
        #pragma unroll
        for (int m = 1; m < 16; m <<= 1) {
            mu = fmaxf(mu, __shfl_xor(mu, m));
            mv = fmaxf(mv, __shfl_xor(mv, m));
        }
        mu = fmaxf(mu, 1e-20f); mv = fmaxf(mv, 1e-20f);
        const float invu = 31.f / mu, su = mu * (1.f / 31.f);
        const float invv = 31.f / mv, sv = mv * (1.f / 31.f);
        const int row = w * 16 + hi * 4 + j;
        uint8_t* lu = ldsu + row * LROW + lane15;
        uint8_t* lv = ldsv + row * LROW + lane15;
        #pragma unroll
        for (int tt = 0; tt < 9; ++tt) {
            lu[16 * tt] = (uint8_t)(uint32_t)(acc[tt][j]      * invu + 32.5f);
            lv[16 * tt] = (uint8_t)(uint32_t)(acc[10 + tt][j] * invv + 32.5f);
        }
        if (lane15 == 0) {
            // col 144 (tile 9 is real only at lane15==0); cols 145..159 are
            // padded zeros and MUST NOT be staged (scale/next-row overlap).
            lu[144] = (uint8_t)(uint32_t)(acc[9][j]  * invu + 32.5f);
            lv[144] = (uint8_t)(uint32_t)(acc[19][j] * invv + 32.5f);
            *(float*)(ldsu + row * LROW + 148) = su;
            *(float*)(ldsv + row * LROW + 148) = sv;
        }
    }
    __syncthreads();

    // repack + coalesced copy-out: idx in [0,512): row=idx>>3, chunk c=idx&7
    // chunk c<7: u32s 4c..4c+3 = cols 20c..20c+19; c==7: vals 140-144 + scale
    char* ug = (char*)u + (size_t)n0blk * MROWB;
    char* vg = (char*)v + (size_t)n0blk * MROWB;
    const bool full = (n0blk + 64 <= nNodes);
    #pragma unroll
    for (int i = 0; i < 2; ++i) {
        const int idx = i * 256 + t;
        const int row = idx >> 3, c = idx & 7;
        if (!full && n0blk + row >= nNodes) continue;
        #pragma unroll
        for (int tab = 0; tab < 2; ++tab) {
            const uint8_t* lr = (tab ? ldsv : ldsu) + row * LROW;
            uint4 o;
            if (c < 7) {
                const uint32_t* wp = (const uint32_t*)(lr + 20 * c);
                const uint32_t b0 = wp[0], b1_ = wp[1], b2 = wp[2], b3 = wp[3], b4 = wp[4];
                o.x = (b0 & 63u) | (((b0 >> 8) & 63u) << 6) | (((b0 >> 16) & 63u) << 12)
                    | (((b0 >> 24) & 63u) << 18) | ((b1_ & 63u) << 24);
                o.y = ((b1_ >> 8) & 63u) | (((b1_ >> 16) & 63u) << 6) | (((b1_ >> 24) & 63u) << 12)
                    | ((b2 & 63u) << 18) | (((b2 >> 8) & 63u) << 24);
                o.z = ((b2 >> 16) & 63u) | (((b2 >> 24) & 63u) << 6) | ((b3 & 63u) << 12)
                    | (((b3 >> 8) & 63u) << 18) | (((b3 >> 16) & 63u) << 24);
                o.w = ((b3 >> 24) & 63u) | ((b4 & 63u) << 6) | (((b4 >> 8) & 63u) << 12)
                    | (((b4 >> 16) & 63u) << 18) | (((b4 >> 24) & 63u) << 24);
            } else {
                const uint32_t w0 = *(const uint32_t*)(lr + 140);
                const uint32_t w1 = *(const uint32_t*)(lr + 144);
                o.x = (w0 & 63u) | (((w0 >> 8) & 63u) << 6) | (((w0 >> 16) & 63u) << 12)
                    | (((w0 >> 24) & 63u) << 18) | ((w1 & 63u) << 24);
                o.y = *(const uint32_t*)(lr + 148);       // f32 scale
                o.z = 0u; o.w = 0u;
            }
            *(uint4*)((tab ? vg : ug) + 16 * idx) = o;
        }
    }
}

// ---------------------------------------------------------------------------
// edge_int6: 4 lanes per edge, 2 edges per group, 32 edges per wave.
//   Lane r reads u32s [8r,8r+8) (2 uint4) of u'[src] and v'[dst] rows.
//   Each u32 = 5 vals at bits 6k; col = 40r + 5*lw + k; w2 zero-padded
//   past col 144 makes scale/pad words contribute exactly 0.
//   Scale = u32 idx 29 = lane 3's 2nd uint4 .y; broadcast via shfl.
// ---------------------------------------------------------------------------
__global__ void __launch_bounds__(256)
edge_int6(const uint32_t* __restrict__ pairs,
          const uint8_t* __restrict__ u, const uint8_t* __restrict__ v,
          const float* __restrict__ w2p, const float* __restrict__ b2,
          float* __restrict__ out, int E)
{
    const int t = threadIdx.x;
    const int lane = t & 63;
    const int r = lane & 3;
    const int grp = lane >> 2;
    const int wid = blockIdx.x * (blockDim.x >> 6) + (t >> 6);
    const int base = wid * 32;
    const int e0 = base + grp, e1 = base + 16 + grp;
    const bool ok0 = e0 < E, ok1 = e1 < E;
    const float bias2 = *b2;

    const uint32_t pr0 = pairs[ok0 ? e0 : 0];
    const uint32_t pr1 = pairs[ok1 ? e1 : 0];

    const uint4* ua = (const uint4*)(u + (pr0 >> 16)     * (uint32_t)MROWB) + 2 * r;
    const uint4* va = (const uint4*)(v + (pr0 & 0xFFFFu) * (uint32_t)MROWB) + 2 * r;
    const uint4* ub = (const uint4*)(u + (pr1 >> 16)     * (uint32_t)MROWB) + 2 * r;
    const uint4* vb = (const uint4*)(v + (pr1 & 0xFFFFu) * (uint32_t)MROWB) + 2 * r;
    const uint4 UA0 = ua[0], UA1 = ua[1];
    const uint4 VA0 = va[0], VA1 = va[1];
    const uint4 UB0 = ub[0], UB1 = ub[1];
    const uint4 VB0 = vb[0], VB1 = vb[1];

    // scales: u32 idx 29 -> lane r=3, 2nd uint4, component y
    const int l3 = lane | 3;
    const float su0 = __shfl(__uint_as_float(UA1.y), l3);
    const float sv0 = __shfl(__uint_as_float(VA1.y), l3);
    const float su1 = __shfl(__uint_as_float(UB1.y), l3);
    const float sv1 = __shfl(__uint_as_float(VB1.y), l3);
    const float off0 = -32.f * (su0 + sv0);
    const float off1 = -32.f * (su1 + sv1);

    uint32_t uw0[8] = {UA0.x, UA0.y, UA0.z, UA0.w, UA1.x, UA1.y, UA1.z, UA1.w};
    uint32_t vw0[8] = {VA0.x, VA0.y, VA0.z, VA0.w, VA1.x, VA1.y, VA1.z, VA1.w};
    uint32_t uw1[8] = {UB0.x, UB0.y, UB0.z, UB0.w, UB1.x, UB1.y, UB1.z, UB1.w};
    uint32_t vw1[8] = {VB0.x, VB0.y, VB0.z, VB0.w, VB1.x, VB1.y, VB1.z, VB1.w};

    const float* w2b = w2p + 40 * r;
    float acc0 = 0.f, acc1 = 0.f;
    #pragma unroll
    for (int lw = 0; lw < 8; ++lw) {
        #pragma unroll
        for (int k = 0; k < 5; ++k) {
            const float w2v = w2b[5 * lw + k];
            const float uf0 = (float)((uw0[lw] >> (6 * k)) & 63u);
            const float vf0 = (float)((vw0[lw] >> (6 * k)) & 63u);
            float tv0 = fmaf(su0, uf0, fmaf(sv0, vf0, off0));
            tv0 = fmaxf(tv0, 0.f);
            acc0 = fmaf(tv0, w2v, acc0);
            const float uf1 = (float)((uw1[lw] >> (6 * k)) & 63u);
            const float vf1 = (float)((vw1[lw] >> (6 * k)) & 63u);
            float tv1 = fmaf(su1, uf1, fmaf(sv1, vf1, off1));
            tv1 = fmaxf(tv1, 0.f);
            acc1 = fmaf(tv1, w2v, acc1);
        }
    }
    acc0 += __shfl_xor(acc0, 1);
    acc0 += __shfl_xor(acc0, 2);
    acc1 += __shfl_xor(acc1, 1);
    acc1 += __shfl_xor(acc1, 2);
    if (r == 0 && ok0) out[e0] = 1.f / (1.f + __expf(-(acc0 + bias2)));
    if (r == 0 && ok1) out[e1] = 1.f / (1.f + __expf(-(acc1 + bias2)));
}

// ---------------------------------------------------------------------------
// fallback_kernel: direct per-edge compute (ws too small or nNodes > 65536)
// ---------------------------------------------------------------------------
__global__ void __launch_bounds__(256)
fallback_kernel(const void* __restrict__ eiv, const float* __restrict__ h,
                const float* __restrict__ cancer, const float* __restrict__ causal,
                const float* __restrict__ W1, const float* __restrict__ b1,
                const float* __restrict__ W2, const float* __restrict__ b2,
                float* __restrict__ out, int E)
{
    const int lane = threadIdx.x & 63;
    const int wpb  = blockDim.x >> 6;
    const int wid  = blockIdx.x * wpb + (threadIdx.x >> 6);
    const int nW   = gridDim.x * wpb;
    const uint32_t* p32 = (const uint32_t*)eiv;
    const uint32_t o = p32[1] | p32[3] | p32[5] | p32[7] | p32[9] | p32[11] | p32[13] | p32[15];
    const int is64 = (o == 0u);
    const long long* e64 = (const long long*)eiv;
    const int*       e32 = (const int*)eiv;
    const float bias2 = *b2;

    for (int e = wid; e < E; e += nW) {
        long long src, dst;
        if (is64) { src = e64[e]; dst = e64[(size_t)E + e]; }
        else      { src = e32[e]; dst = e32[(size_t)E + e]; }
        const float ci = causal[src], cj = causal[dst];
        float acc0 = 0.f, acc1 = 0.f, acc2 = 0.f;
        const int j0 = lane, j1 = lane + 64, j2 = lane + 128;
        for (int k = 0; k < 291; ++k) {
            float f;
            if      (k < 128) f = h[(size_t)src * 128 + k];
            else if (k < 256) f = h[(size_t)dst * 128 + (k - 128)];
            else if (k < 288) f = cancer[k - 256];
            else if (k == 288) f = ci;
            else if (k == 289) f = cj;
            else               f = ci - cj;
            const float* wr = W1 + (size_t)k * HID;
            acc0 = fmaf(f, wr[j0], acc0);
            acc1 = fmaf(f, wr[j1], acc1);
            if (j2 < HID) acc2 = fmaf(f, wr[j2], acc2);
        }
        float partial = fmaxf(acc0 + b1[j0], 0.f) * W2[j0]
                      + fmaxf(acc1 + b1[j1], 0.f) * W2[j1];
        if (j2 < HID) partial += fmaxf(acc2 + b1[j2], 0.f) * W2[j2];
        #pragma unroll
        for (int m = 32; m; m >>= 1) partial += __shfl_xor(partial, m, 64);
        if (lane == 0) out[e] = 1.f / (1.f + __expf(-(partial + bias2)));
    }
}

// ---------------------------------------------------------------------------
extern "C" void kernel_launch(void* const* d_in, const int* in_sizes, int n_in,
                              void* d_out, int out_size, void* d_ws, size_t ws_size,
                              hipStream_t stream)
{
    const float* h      = (const float*)d_in[0];
    const void*  ei     = d_in[1];
    const float* cancer = (const float*)d_in[2];
    const float* causal = (const float*)d_in[3];
    const float* W1     = (const float*)d_in[4];
    const float* b1     = (const float*)d_in[5];
    const float* W2     = (const float*)d_in[6];
    const float* b2     = (const float*)d_in[7];
    float* outp = (float*)d_out;

    const int nNodes = in_sizes[0] / EMBED;
    const int E      = in_sizes[1] / 2;

    // workspace layout
    const size_t WPB_OFF   = 8192;                      // 80 KB -> ends 90112
    const size_t PAIRS_OFF = 98304;
    const size_t pairsB    = ((size_t)E * 4 + 255) & ~(size_t)255;
    const size_t tabB      = (size_t)nNodes * MROWB;    // 6.4 MB each
    const size_t U_OFF     = PAIRS_OFF + pairsB;
    const size_t V_OFF     = (U_OFF + tabB + 255) & ~(size_t)255;
    const size_t need      = V_OFF + tabB;

    char* ws = (char*)d_ws;
    float* b1p  = (float*)(ws + 1024);
    float* wci  = (float*)(ws + 2048);
    float* wcj  = (float*)(ws + 3072);
    float* w2p  = (float*)(ws + 4096);
    short* Wpb  = (short*)(ws + WPB_OFF);

    if (ws_size >= need && nNodes <= 65536) {
        uint32_t* pairs = (uint32_t*)(ws + PAIRS_OFF);
        uint8_t*  u     = (uint8_t*)(ws + U_OFF);
        uint8_t*  v     = (uint8_t*)(ws + V_OFF);

        const int P = (E + 255) / 256;
        prep_fused<<<P + 161, 256, 0, stream>>>(cancer, W1, b1, W2, ei, E, P,
                                                b1p, wci, wcj, w2p, Wpb, pairs);
        proj_mfma<<<(nNodes + 63) / 64, 256, 0, stream>>>(h, Wpb, causal, b1p,
                                                          wci, wcj, u, v, nNodes);
        const int waves  = (E + 31) / 32;
        const int blocks = (waves + 3) / 4;
        edge_int6<<<blocks, 256, 0, stream>>>(pairs, u, v, w2p, b2, outp, E);
    } else {
        fallback_kernel<<<2048, 256, 0, stream>>>(ei, h, cancer, causal, W1, b1, W2, b2,
                                                  outp, E);
    }
}

// Round 10
// 81.154 us; speedup vs baseline: 1.9222x; 1.0106x over previous
//
#include <hip/hip_runtime.h>
#include <hip/hip_bf16.h>
#include <stdint.h>

#define EMBED 128
#define HID 145
#define HSTR 160            // padded col count per table (MFMA tiles)
#define NTILE 20            // 320 output cols / 16
#define KCH 4               // 128 K / 32
#define MROWB 128           // int6 row: 29 u32 packed vals (cols 0..144) + f32 scale @ u32 29
#define LROW 152            // LDS staging row stride: 145 bytes + 3 pad + f32 scale @ 148
#define HS4ROW 33           // h-staging LDS row stride in float4 (528 B: breaks 512B bank alias)

typedef __attribute__((ext_vector_type(8))) short short8;
typedef __attribute__((ext_vector_type(4))) float f32x4;

__device__ __forceinline__ uint16_t f2bf(float f) {
    uint32_t x = __float_as_uint(f);
    x += 0x7FFFu + ((x >> 16) & 1u);          // round-to-nearest-even
    return (uint16_t)(x >> 16);
}
__device__ __forceinline__ short f2bf_cvt(float f) {
    union { __bf16 h; short s; } u_;
    u_.h = (__bf16)f;
    return u_.s;
}

// ---------------------------------------------------------------------------
// prep_fused: blocks [0,P): pack pairs[e]=(src<<16)|dst
//             blocks [P,P+160): pack W1 into bf16 B-fragment order (Wpb)
//             block P+160: fold cancer/b1/causal cols; plain zero-padded W2
// ---------------------------------------------------------------------------
__global__ void __launch_bounds__(256)
prep_fused(const float* __restrict__ cancer, const float* __restrict__ W1,
           const float* __restrict__ b1, const float* __restrict__ W2,
           const void* __restrict__ eiv, int E, int P,
           float* __restrict__ b1p, float* __restrict__ wci,
           float* __restrict__ wcj, float* __restrict__ w2p,
           short* __restrict__ Wpb, uint32_t* __restrict__ pairs)
{
    const int t = threadIdx.x;
    const int b = blockIdx.x;
    if (b < P) {
        // int64 indices < 65536 => every odd 32-bit word is zero.
        const uint32_t* pw = (const uint32_t*)eiv;
        const uint32_t odd = pw[1] | pw[3] | pw[5] | pw[7] | pw[9] | pw[11] | pw[13] | pw[15];
        const int is64 = (odd == 0u);
        const int e = b * 256 + t;
        if (e < E) {
            uint32_t src, dst;
            if (is64) {
                const long long* e64 = (const long long*)eiv;
                src = (uint32_t)e64[e]; dst = (uint32_t)e64[(size_t)E + e];
            } else {
                const uint32_t* e32 = (const uint32_t*)eiv;
                src = e32[e];           dst = e32[(size_t)E + e];
            }
            pairs[e] = (src << 16) | (dst & 0xFFFFu);
        }
        return;
    }
    if (b < P + 160) {
        const int idx = (b - P) * 256 + t;            // < 40960
        const int reg  = idx & 7;
        const int lane = (idx >> 3) & 63;
        const int tl   = idx >> 9;                    // 0..79
        const int tt   = tl % NTILE;
        const int kc   = tl / NTILE;
        const int k    = kc * 32 + (lane >> 4) * 8 + reg;
        const int col  = tt * 16 + (lane & 15);
        float val = 0.f;
        if (col < HID)                             val = W1[(size_t)k * HID + col];
        else if (col >= HSTR && col < HSTR + HID)  val = W1[(size_t)(EMBED + k) * HID + (col - HSTR)];
        Wpb[idx] = (short)f2bf(val);
        return;
    }
    // smalls
    if (t < HSTR) {
        float bv = 0.f, a = 0.f, bb = 0.f, w2 = 0.f;
        if (t < HID) {
            float s = b1[t];
            #pragma unroll
            for (int k = 0; k < 32; ++k)
                s = fmaf(cancer[k], W1[(size_t)(2 * EMBED + k) * HID + t], s);
            bv = s;
            a  = W1[(size_t)288 * HID + t] + W1[(size_t)290 * HID + t];  // c_i + diff
            bb = W1[(size_t)289 * HID + t] - W1[(size_t)290 * HID + t];  // c_j - diff
            w2 = W2[t];
        }
        b1p[t] = bv; wci[t] = a; wcj[t] = bb; w2p[t] = w2;   // plain col order
    }
}

// ---------------------------------------------------------------------------
// proj_mfma: u'[n] = h[n]@A + b1p + causal[n]*wci   (int6 rowscale, 128 B row)
//            v'[n] = h[n]@B        + causal[n]*wcj
//   r10 FIX: h is staged block-wide into LDS with dense coalesced float4
//   copies (4 KB/instr) instead of per-lane scattered 16B gathers (16 lines
//   per instr, latency-bound at 565 GB/s -> was 45 us). A-fragments then come
//   from ds_read_b128 at padded stride 528 B (exactly at the b128 bank floor).
//   Epilogue (unchanged logic): fold -> per-row absmax -> int6 quantize ->
//   LDS col-order bytes (cols 0..144 only; scale @148) -> repack 5 vals/u32
//   -> coalesced uint4 copy-out. LDS buffer reused between phases.
// ---------------------------------------------------------------------------
__global__ void __launch_bounds__(256)
proj_mfma(const float* __restrict__ h, const short* __restrict__ Wpb,
          const float* __restrict__ causal, const float* __restrict__ b1p,
          const float* __restrict__ wci, const float* __restrict__ wcj,
          uint8_t* __restrict__ u, uint8_t* __restrict__ v, int nNodes)
{
    __shared__ __align__(16) uint8_t smem[64 * HS4ROW * 16];   // 33792 B
    float4* hs4 = (float4*)smem;

    const int t = threadIdx.x;
    const int lane = t & 63;
    const int w = t >> 6;
    const int lane15 = lane & 15, hi = lane >> 4;
    const int n0blk = blockIdx.x * 64;
    const int nbase = n0blk + w * 16;

    // ---- stage h: 64 rows x 512 B, dense coalesced copies
    const float4* hsrc = (const float4*)(h + (size_t)n0blk * EMBED);
    if (n0blk + 64 <= nNodes) {
        #pragma unroll
        for (int k = 0; k < 8; ++k) {
            const int f = k * 256 + t;                 // float4 idx 0..2047
            hs4[(f >> 5) * HS4ROW + (f & 31)] = hsrc[f];
        }
    } else {
        #pragma unroll
        for (int k = 0; k < 8; ++k) {
            const int f = k * 256 + t;
            const int row = f >> 5;
            float4 val = make_float4(0.f, 0.f, 0.f, 0.f);
            if (n0blk + row < nNodes) val = hsrc[f];
            hs4[row * HS4ROW + (f & 31)] = val;
        }
    }
    __syncthreads();

    // ---- A fragments from LDS (row = block-local node, hi = k-slice)
    const float4* hrow4 = hs4 + (w * 16 + lane15) * HS4ROW + hi * 2;
    short8 afr[KCH];
    #pragma unroll
    for (int kc = 0; kc < KCH; ++kc) {
        const float4 x = hrow4[kc * 8];
        const float4 y = hrow4[kc * 8 + 1];
        short8 a;
        a[0] = f2bf_cvt(x.x); a[1] = f2bf_cvt(x.y);
        a[2] = f2bf_cvt(x.z); a[3] = f2bf_cvt(x.w);
        a[4] = f2bf_cvt(y.x); a[5] = f2bf_cvt(y.y);
        a[6] = f2bf_cvt(y.z); a[7] = f2bf_cvt(y.w);
        afr[kc] = a;
    }

    f32x4 acc[NTILE];
    #pragma unroll
    for (int tt = 0; tt < NTILE; ++tt) acc[tt] = (f32x4){0.f, 0.f, 0.f, 0.f};

    const short8* bp = (const short8*)Wpb;
    #pragma unroll
    for (int kc = 0; kc < KCH; ++kc) {
        #pragma unroll
        for (int tt = 0; tt < NTILE; ++tt) {
            const short8 b = bp[(kc * NTILE + tt) * 64 + lane];
            acc[tt] = __builtin_amdgcn_mfma_f32_16x16x32_bf16(afr[kc], b, acc[tt], 0, 0, 0);
        }
    }

    float cz[4];
    #pragma unroll
    for (int j = 0; j < 4; ++j) {
        const int n = nbase + hi * 4 + j;
        cz[j] = (n < nNodes) ? causal[n] : 0.f;
    }

    // fold bias/causal terms in place
    #pragma unroll
    for (int tt = 0; tt < NTILE; ++tt) {
        const int col = tt * 16 + lane15;
        const bool isU = (tt < 10);
        const int ccol = isU ? col : col - HSTR;
        const float addB = isU ? b1p[ccol] : 0.f;
        const float addC = isU ? wci[ccol] : wcj[ccol];
        #pragma unroll
        for (int j = 0; j < 4; ++j)
            acc[tt][j] = acc[tt][j] + fmaf(cz[j], addC, addB);
    }

    __syncthreads();   // all afr reads done -> safe to reuse smem for staging

    uint8_t* ldsu = smem;
    uint8_t* ldsv = smem + 64 * LROW;

    #pragma unroll
    for (int j = 0; j < 4; ++j) {
        float mu = fmaxf(fmaxf(fmaxf(fabsf(acc[0][j]), fabsf(acc[1][j])),
                               fmaxf(fabsf(acc[2][j]), fabsf(acc[3][j]))),
                         fmaxf(fmaxf(fabsf(acc[4][j]), fabsf(acc[5][j])),
                               fmaxf(fmaxf(fabsf(acc[6][j]), fabsf(acc[7][j])),
                                     fmaxf(fabsf(acc[8][j]), fabsf(acc[9][j])))));
        float mv = fmaxf(fmaxf(fmaxf(fabsf(acc[10][j]), fabsf(acc[11][j])),
                               fmaxf(fabsf(acc[12][j]), fabsf(acc[13][j]))),
                         fmaxf(fmaxf(fabsf(acc[14][j]), fabsf(acc[15][j])),
                               fmaxf(fmaxf(fabsf(acc[16][j]), fabsf(acc[17][j])),
                                     fmaxf(fabsf(acc[18][j]), fabsf(acc[19][j])))));
        #pragma unroll
        for (int m = 1; m < 16; m <<= 1) {
            mu = fmaxf(mu, __shfl_xor(mu, m));
            mv = fmaxf(mv, __shfl_xor(mv, m));
        }
        mu = fmaxf(mu, 1e-20f); mv = fmaxf(mv, 1e-20f);
        const float invu = 31.f / mu, su = mu * (1.f / 31.f);
        const float invv = 31.f / mv, sv = mv * (1.f / 31.f);
        const int row = w * 16 + hi * 4 + j;
        uint8_t* lu = ldsu + row * LROW + lane15;
        uint8_t* lv = ldsv + row * LROW + lane15;
        #pragma unroll
        for (int tt = 0; tt < 9; ++tt) {
            lu[16 * tt] = (uint8_t)(uint32_t)(acc[tt][j]      * invu + 32.5f);
            lv[16 * tt] = (uint8_t)(uint32_t)(acc[10 + tt][j] * invv + 32.5f);
        }
        if (lane15 == 0) {
            // col 144 (tile 9 real only at lane15==0); cols 145..159 are
            // padded zeros and MUST NOT be staged (scale/next-row overlap).
            lu[144] = (uint8_t)(uint32_t)(acc[9][j]  * invu + 32.5f);
            lv[144] = (uint8_t)(uint32_t)(acc[19][j] * invv + 32.5f);
            *(float*)(ldsu + row * LROW + 148) = su;
            *(float*)(ldsv + row * LROW + 148) = sv;
        }
    }
    __syncthreads();

    // repack + coalesced copy-out: idx in [0,512): row=idx>>3, chunk c=idx&7
    // chunk c<7: u32s 4c..4c+3 = cols 20c..20c+19; c==7: vals 140-144 + scale
    char* ug = (char*)u + (size_t)n0blk * MROWB;
    char* vg = (char*)v + (size_t)n0blk * MROWB;
    const bool full = (n0blk + 64 <= nNodes);
    #pragma unroll
    for (int i = 0; i < 2; ++i) {
        const int idx = i * 256 + t;
        const int row = idx >> 3, c = idx & 7;
        if (!full && n0blk + row >= nNodes) continue;
        #pragma unroll
        for (int tab = 0; tab < 2; ++tab) {
            const uint8_t* lr = (tab ? ldsv : ldsu) + row * LROW;
            uint4 o;
            if (c < 7) {
                const uint32_t* wp = (const uint32_t*)(lr + 20 * c);
                const uint32_t b0 = wp[0], b1_ = wp[1], b2 = wp[2], b3 = wp[3], b4 = wp[4];
                o.x = (b0 & 63u) | (((b0 >> 8) & 63u) << 6) | (((b0 >> 16) & 63u) << 12)
                    | (((b0 >> 24) & 63u) << 18) | ((b1_ & 63u) << 24);
                o.y = ((b1_ >> 8) & 63u) | (((b1_ >> 16) & 63u) << 6) | (((b1_ >> 24) & 63u) << 12)
                    | ((b2 & 63u) << 18) | (((b2 >> 8) & 63u) << 24);
                o.z = ((b2 >> 16) & 63u) | (((b2 >> 24) & 63u) << 6) | ((b3 & 63u) << 12)
                    | (((b3 >> 8) & 63u) << 18) | (((b3 >> 16) & 63u) << 24);
                o.w = ((b3 >> 24) & 63u) | ((b4 & 63u) << 6) | (((b4 >> 8) & 63u) << 12)
                    | (((b4 >> 16) & 63u) << 18) | (((b4 >> 24) & 63u) << 24);
            } else {
                const uint32_t w0 = *(const uint32_t*)(lr + 140);
                const uint32_t w1 = *(const uint32_t*)(lr + 144);
                o.x = (w0 & 63u) | (((w0 >> 8) & 63u) << 6) | (((w0 >> 16) & 63u) << 12)
                    | (((w0 >> 24) & 63u) << 18) | ((w1 & 63u) << 24);
                o.y = *(const uint32_t*)(lr + 148);       // f32 scale
                o.z = 0u; o.w = 0u;
            }
            *(uint4*)((tab ? vg : ug) + 16 * idx) = o;
        }
    }
}

// ---------------------------------------------------------------------------
// edge_int6: 4 lanes per edge, 2 edges per group, 32 edges per wave.
//   Lane r reads u32s [8r,8r+8) (2 uint4) of u'[src] and v'[dst] rows.
//   Each u32 = 5 vals at bits 6k; col = 40r + 5*lw + k; w2 zero-padded
//   past col 144 makes scale/pad words contribute exactly 0.
//   Scale = u32 idx 29 = lane 3's 2nd uint4 .y; broadcast via shfl.
// ---------------------------------------------------------------------------
__global__ void __launch_bounds__(256)
edge_int6(const uint32_t* __restrict__ pairs,
          const uint8_t* __restrict__ u, const uint8_t* __restrict__ v,
          const float* __restrict__ w2p, const float* __restrict__ b2,
          float* __restrict__ out, int E)
{
    const int t = threadIdx.x;
    const int lane = t & 63;
    const int r = lane & 3;
    const int grp = lane >> 2;
    const int wid = blockIdx.x * (blockDim.x >> 6) + (t >> 6);
    const int base = wid * 32;
    const int e0 = base + grp, e1 = base + 16 + grp;
    const bool ok0 = e0 < E, ok1 = e1 < E;
    const float bias2 = *b2;

    const uint32_t pr0 = pairs[ok0 ? e0 : 0];
    const uint32_t pr1 = pairs[ok1 ? e1 : 0];

    const uint4* ua = (const uint4*)(u + (pr0 >> 16)     * (uint32_t)MROWB) + 2 * r;
    const uint4* va = (const uint4*)(v + (pr0 & 0xFFFFu) * (uint32_t)MROWB) + 2 * r;
    const uint4* ub = (const uint4*)(u + (pr1 >> 16)     * (uint32_t)MROWB) + 2 * r;
    const uint4* vb = (const uint4*)(v + (pr1 & 0xFFFFu) * (uint32_t)MROWB) + 2 * r;
    const uint4 UA0 = ua[0], UA1 = ua[1];
    const uint4 VA0 = va[0], VA1 = va[1];
    const uint4 UB0 = ub[0], UB1 = ub[1];
    const uint4 VB0 = vb[0], VB1 = vb[1];

    // scales: u32 idx 29 -> lane r=3, 2nd uint4, component y
    const int l3 = lane | 3;
    const float su0 = __shfl(__uint_as_float(UA1.y), l3);
    const float sv0 = __shfl(__uint_as_float(VA1.y), l3);
    const float su1 = __shfl(__uint_as_float(UB1.y), l3);
    const float sv1 = __shfl(__uint_as_float(VB1.y), l3);
    const float off0 = -32.f * (su0 + sv0);
    const float off1 = -32.f * (su1 + sv1);

    uint32_t uw0[8] = {UA0.x, UA0.y, UA0.z, UA0.w, UA1.x, UA1.y, UA1.z, UA1.w};
    uint32_t vw0[8] = {VA0.x, VA0.y, VA0.z, VA0.w, VA1.x, VA1.y, VA1.z, VA1.w};
    uint32_t uw1[8] = {UB0.x, UB0.y, UB0.z, UB0.w, UB1.x, UB1.y, UB1.z, UB1.w};
    uint32_t vw1[8] = {VB0.x, VB0.y, VB0.z, VB0.w, VB1.x, VB1.y, VB1.z, VB1.w};

    const float* w2b = w2p + 40 * r;
    float acc0 = 0.f, acc1 = 0.f;
    #pragma unroll
    for (int lw = 0; lw < 8; ++lw) {
        #pragma unroll
        for (int k = 0; k < 5; ++k) {
            const float w2v = w2b[5 * lw + k];
            const float uf0 = (float)((uw0[lw] >> (6 * k)) & 63u);
            const float vf0 = (float)((vw0[lw] >> (6 * k)) & 63u);
            float tv0 = fmaf(su0, uf0, fmaf(sv0, vf0, off0));
            tv0 = fmaxf(tv0, 0.f);
            acc0 = fmaf(tv0, w2v, acc0);
            const float uf1 = (float)((uw1[lw] >> (6 * k)) & 63u);
            const float vf1 = (float)((vw1[lw] >> (6 * k)) & 63u);
            float tv1 = fmaf(su1, uf1, fmaf(sv1, vf1, off1));
            tv1 = fmaxf(tv1, 0.f);
            acc1 = fmaf(tv1, w2v, acc1);
        }
    }
    acc0 += __shfl_xor(acc0, 1);
    acc0 += __shfl_xor(acc0, 2);
    acc1 += __shfl_xor(acc1, 1);
    acc1 += __shfl_xor(acc1, 2);
    if (r == 0 && ok0) out[e0] = 1.f / (1.f + __expf(-(acc0 + bias2)));
    if (r == 0 && ok1) out[e1] = 1.f / (1.f + __expf(-(acc1 + bias2)));
}

// ---------------------------------------------------------------------------
// fallback_kernel: direct per-edge compute (ws too small or nNodes > 65536)
// ---------------------------------------------------------------------------
__global__ void __launch_bounds__(256)
fallback_kernel(const void* __restrict__ eiv, const float* __restrict__ h,
                const float* __restrict__ cancer, const float* __restrict__ causal,
                const float* __restrict__ W1, const float* __restrict__ b1,
                const float* __restrict__ W2, const float* __restrict__ b2,
                float* __restrict__ out, int E)
{
    const int lane = threadIdx.x & 63;
    const int wpb  = blockDim.x >> 6;
    const int wid  = blockIdx.x * wpb + (threadIdx.x >> 6);
    const int nW   = gridDim.x * wpb;
    const uint32_t* p32 = (const uint32_t*)eiv;
    const uint32_t o = p32[1] | p32[3] | p32[5] | p32[7] | p32[9] | p32[11] | p32[13] | p32[15];
    const int is64 = (o == 0u);
    const long long* e64 = (const long long*)eiv;
    const int*       e32 = (const int*)eiv;
    const float bias2 = *b2;

    for (int e = wid; e < E; e += nW) {
        long long src, dst;
        if (is64) { src = e64[e]; dst = e64[(size_t)E + e]; }
        else      { src = e32[e]; dst = e32[(size_t)E + e]; }
        const float ci = causal[src], cj = causal[dst];
        float acc0 = 0.f, acc1 = 0.f, acc2 = 0.f;
        const int j0 = lane, j1 = lane + 64, j2 = lane + 128;
        for (int k = 0; k < 291; ++k) {
            float f;
            if      (k < 128) f = h[(size_t)src * 128 + k];
            else if (k < 256) f = h[(size_t)dst * 128 + (k - 128)];
            else if (k < 288) f = cancer[k - 256];
            else if (k == 288) f = ci;
            else if (k == 289) f = cj;
            else               f = ci - cj;
            const float* wr = W1 + (size_t)k * HID;
            acc0 = fmaf(f, wr[j0], acc0);
            acc1 = fmaf(f, wr[j1], acc1);
            if (j2 < HID) acc2 = fmaf(f, wr[j2], acc2);
        }
        float partial = fmaxf(acc0 + b1[j0], 0.f) * W2[j0]
                      + fmaxf(acc1 + b1[j1], 0.f) * W2[j1];
        if (j2 < HID) partial += fmaxf(acc2 + b1[j2], 0.f) * W2[j2];
        #pragma unroll
        for (int m = 32; m; m >>= 1) partial += __shfl_xor(partial, m, 64);
        if (lane == 0) out[e] = 1.f / (1.f + __expf(-(partial + bias2)));
    }
}

// ---------------------------------------------------------------------------
extern "C" void kernel_launch(void* const* d_in, const int* in_sizes, int n_in,
                              void* d_out, int out_size, void* d_ws, size_t ws_size,
                              hipStream_t stream)
{
    const float* h      = (const float*)d_in[0];
    const void*  ei     = d_in[1];
    const float* cancer = (const float*)d_in[2];
    const float* causal = (const float*)d_in[3];
    const float* W1     = (const float*)d_in[4];
    const float* b1     = (const float*)d_in[5];
    const float* W2     = (const float*)d_in[6];
    const float* b2     = (const float*)d_in[7];
    float* outp = (float*)d_out;

    const int nNodes = in_sizes[0] / EMBED;
    const int E      = in_sizes[1] / 2;

    // workspace layout
    const size_t WPB_OFF   = 8192;                      // 80 KB -> ends 90112
    const size_t PAIRS_OFF = 98304;
    const size_t pairsB    = ((size_t)E * 4 + 255) & ~(size_t)255;
    const size_t tabB      = (size_t)nNodes * MROWB;    // 6.4 MB each
    const size_t U_OFF     = PAIRS_OFF + pairsB;
    const size_t V_OFF     = (U_OFF + tabB + 255) & ~(size_t)255;
    const size_t need      = V_OFF + tabB;

    char* ws = (char*)d_ws;
    float* b1p  = (float*)(ws + 1024);
    float* wci  = (float*)(ws + 2048);
    float* wcj  = (float*)(ws + 3072);
    float* w2p  = (float*)(ws + 4096);
    short* Wpb  = (short*)(ws + WPB_OFF);

    if (ws_size >= need && nNodes <= 65536) {
        uint32_t* pairs = (uint32_t*)(ws + PAIRS_OFF);
        uint8_t*  u     = (uint8_t*)(ws + U_OFF);
        uint8_t*  v     = (uint8_t*)(ws + V_OFF);

        const int P = (E + 255) / 256;
        prep_fused<<<P + 161, 256, 0, stream>>>(cancer, W1, b1, W2, ei, E, P,
                                                b1p, wci, wcj, w2p, Wpb, pairs);
        proj_mfma<<<(nNodes + 63) / 64, 256, 0, stream>>>(h, Wpb, causal, b1p,
                                                          wci, wcj, u, v, nNodes);
        const int waves  = (E + 31) / 32;
        const int blocks = (waves + 3) / 4;
        edge_int6<<<blocks, 256, 0, stream>>>(pairs, u, v, w2p, b2, outp, E);
    } else {
        fallback_kernel<<<2048, 256, 0, stream>>>(ei, h, cancer, causal, W1, b1, W2, b2,
                                                  outp, E);
    }
}

// Round 11
// 66.595 us; speedup vs baseline: 2.3425x; 1.2186x over previous
//
#include <hip/hip_runtime.h>
#include <hip/hip_bf16.h>
#include <stdint.h>

#define EMBED 128
#define HID 145
#define HSTR 160            // padded col count per table (MFMA tiles)
#define NTILE 20            // 320 output cols / 16
#define KCH 4               // 128 K / 32
#define MROWB 128           // int6 row: 29 u32 packed vals (cols 0..144) + f32 scale @ u32 29
#define LROW 152            // LDS staging row stride: 145 bytes + 3 pad + f32 scale @ 148
#define HB2ROW 272          // bf16 h-staging row stride in bytes (256 + 16 pad)

typedef __attribute__((ext_vector_type(8))) short short8;
typedef __attribute__((ext_vector_type(4))) float f32x4;

__device__ __forceinline__ uint16_t f2bf(float f) {
    uint32_t x = __float_as_uint(f);
    x += 0x7FFFu + ((x >> 16) & 1u);          // round-to-nearest-even
    return (uint16_t)(x >> 16);
}
__device__ __forceinline__ short f2bf_cvt(float f) {
    union { __bf16 h; short s; } u_;
    u_.h = (__bf16)f;
    return u_.s;
}

// ---------------------------------------------------------------------------
// prep_fused: blocks [0,P): pack pairs[e]=(src<<16)|dst
//             blocks [P,P+160): pack W1 into bf16 B-fragment order (Wpb)
//             block P+160: fold cancer/b1/causal cols; plain zero-padded W2
// ---------------------------------------------------------------------------
__global__ void __launch_bounds__(256)
prep_fused(const float* __restrict__ cancer, const float* __restrict__ W1,
           const float* __restrict__ b1, const float* __restrict__ W2,
           const void* __restrict__ eiv, int E, int P,
           float* __restrict__ b1p, float* __restrict__ wci,
           float* __restrict__ wcj, float* __restrict__ w2p,
           short* __restrict__ Wpb, uint32_t* __restrict__ pairs)
{
    const int t = threadIdx.x;
    const int b = blockIdx.x;
    if (b < P) {
        // int64 indices < 65536 => every odd 32-bit word is zero.
        const uint32_t* pw = (const uint32_t*)eiv;
        const uint32_t odd = pw[1] | pw[3] | pw[5] | pw[7] | pw[9] | pw[11] | pw[13] | pw[15];
        const int is64 = (odd == 0u);
        const int e = b * 256 + t;
        if (e < E) {
            uint32_t src, dst;
            if (is64) {
                const long long* e64 = (const long long*)eiv;
                src = (uint32_t)e64[e]; dst = (uint32_t)e64[(size_t)E + e];
            } else {
                const uint32_t* e32 = (const uint32_t*)eiv;
                src = e32[e];           dst = e32[(size_t)E + e];
            }
            pairs[e] = (src << 16) | (dst & 0xFFFFu);
        }
        return;
    }
    if (b < P + 160) {
        const int idx = (b - P) * 256 + t;            // < 40960
        const int reg  = idx & 7;
        const int lane = (idx >> 3) & 63;
        const int tl   = idx >> 9;                    // 0..79
        const int tt   = tl % NTILE;
        const int kc   = tl / NTILE;
        const int k    = kc * 32 + (lane >> 4) * 8 + reg;
        const int col  = tt * 16 + (lane & 15);
        float val = 0.f;
        if (col < HID)                             val = W1[(size_t)k * HID + col];
        else if (col >= HSTR && col < HSTR + HID)  val = W1[(size_t)(EMBED + k) * HID + (col - HSTR)];
        Wpb[idx] = (short)f2bf(val);
        return;
    }
    // smalls
    if (t < HSTR) {
        float bv = 0.f, a = 0.f, bb = 0.f, w2 = 0.f;
        if (t < HID) {
            float s = b1[t];
            #pragma unroll
            for (int k = 0; k < 32; ++k)
                s = fmaf(cancer[k], W1[(size_t)(2 * EMBED + k) * HID + t], s);
            bv = s;
            a  = W1[(size_t)288 * HID + t] + W1[(size_t)290 * HID + t];  // c_i + diff
            bb = W1[(size_t)289 * HID + t] - W1[(size_t)290 * HID + t];  // c_j - diff
            w2 = W2[t];
        }
        b1p[t] = bv; wci[t] = a; wcj[t] = bb; w2p[t] = w2;   // plain col order
    }
}

// ---------------------------------------------------------------------------
// proj_mfma: u'[n] = h[n]@A + b1p + causal[n]*wci   (int6 rowscale, 128 B row)
//            v'[n] = h[n]@B        + causal[n]*wcj
//   r11 RESTRUCTURE (B-path was the bottleneck: r9==r10==45us, MfmaUtil 3%):
//   wave w owns 5 output tiles [5w,5w+5) x all 64 block nodes (4 groups of
//   16). Per kc: 5 B-fragment global loads (batched, reused across 4 groups
//   -> 20 B-loads/wave instead of 80) + 4 A ds_read_b128 from bf16-staged h
//   (1 read = 1 fragment, converts done once in the coalesced staging pass).
//   Per-row quantize max now spans 2 waves per table -> pmax LDS array +
//   one barrier. Byte staging: wave writes cols [80*(w&1), ...) of its
//   table, guard ccol<145 keeps scale@148 and pads untouched (r9 layout).
// ---------------------------------------------------------------------------
__global__ void __launch_bounds__(256)
proj_mfma(const float* __restrict__ h, const short* __restrict__ Wpb,
          const float* __restrict__ causal, const float* __restrict__ b1p,
          const float* __restrict__ wci, const float* __restrict__ wcj,
          uint8_t* __restrict__ u, uint8_t* __restrict__ v, int nNodes)
{
    __shared__ __align__(16) uint8_t smem[2 * 64 * LROW];   // 19456 B (>= 64*HB2ROW)
    __shared__ float pmax[2][2][64];                        // [table][wave-half][row]

    const int t = threadIdx.x;
    const int lane = t & 63;
    const int w = t >> 6;
    const int lane15 = lane & 15, hi = lane >> 4;
    const int n0blk = blockIdx.x * 64;
    const bool full = (n0blk + 64 <= nNodes);

    // ---- stage h as bf16: 64 rows x 256 B, dense coalesced copies
    const float4* hsrc = (const float4*)(h + (size_t)n0blk * EMBED);
    if (full) {
        #pragma unroll
        for (int k = 0; k < 8; ++k) {
            const int f = k * 256 + t;                 // float4 idx 0..2047
            const float4 x = hsrc[f];
            const uint32_t lo = (uint32_t)(uint16_t)f2bf_cvt(x.x)
                              | ((uint32_t)(uint16_t)f2bf_cvt(x.y) << 16);
            const uint32_t hg = (uint32_t)(uint16_t)f2bf_cvt(x.z)
                              | ((uint32_t)(uint16_t)f2bf_cvt(x.w) << 16);
            *(uint2*)(smem + (f >> 5) * HB2ROW + (f & 31) * 8) = make_uint2(lo, hg);
        }
    } else {
        #pragma unroll
        for (int k = 0; k < 8; ++k) {
            const int f = k * 256 + t;
            const int row = f >> 5;
            float4 x = make_float4(0.f, 0.f, 0.f, 0.f);
            if (n0blk + row < nNodes) x = hsrc[f];
            const uint32_t lo = (uint32_t)(uint16_t)f2bf_cvt(x.x)
                              | ((uint32_t)(uint16_t)f2bf_cvt(x.y) << 16);
            const uint32_t hg = (uint32_t)(uint16_t)f2bf_cvt(x.z)
                              | ((uint32_t)(uint16_t)f2bf_cvt(x.w) << 16);
            *(uint2*)(smem + row * HB2ROW + (f & 31) * 8) = make_uint2(lo, hg);
        }
    }
    __syncthreads();

    // ---- MFMA: acc[group g][tile i], tile tt = 5w+i, nodes g*16+row-in-frag
    const int w5 = 5 * w;
    const uint8_t* habase = smem + lane15 * HB2ROW + hi * 16;

    f32x4 acc[4][5];
    #pragma unroll
    for (int g = 0; g < 4; ++g)
        #pragma unroll
        for (int i = 0; i < 5; ++i) acc[g][i] = (f32x4){0.f, 0.f, 0.f, 0.f};

    const short8* bp = (const short8*)Wpb;
    #pragma unroll
    for (int kc = 0; kc < KCH; ++kc) {
        short8 bfr[5];
        #pragma unroll
        for (int i = 0; i < 5; ++i)
            bfr[i] = bp[(kc * NTILE + w5 + i) * 64 + lane];
        #pragma unroll
        for (int g = 0; g < 4; ++g) {
            const short8 a = *(const short8*)(habase + g * 16 * HB2ROW + kc * 64);
            #pragma unroll
            for (int i = 0; i < 5; ++i)
                acc[g][i] = __builtin_amdgcn_mfma_f32_16x16x32_bf16(a, bfr[i], acc[g][i], 0, 0, 0);
        }
    }

    // ---- fold bias/causal terms (addB/addC hoisted per tile)
    const int tb = w >> 1, hf = w & 1;                  // table (0=u,1=v), half
    float addB[5], addC[5];
    #pragma unroll
    for (int i = 0; i < 5; ++i) {
        const int col = (w5 + i) * 16 + lane15;
        const int ccol = tb ? col - HSTR : col;
        addB[i] = tb ? 0.f : b1p[ccol];
        addC[i] = tb ? wcj[ccol] : wci[ccol];
    }
    #pragma unroll
    for (int g = 0; g < 4; ++g) {
        float cz[4];
        #pragma unroll
        for (int j = 0; j < 4; ++j) {
            const int n = n0blk + g * 16 + hi * 4 + j;
            cz[j] = (n < nNodes) ? causal[n] : 0.f;
        }
        #pragma unroll
        for (int i = 0; i < 5; ++i)
            #pragma unroll
            for (int j = 0; j < 4; ++j)
                acc[g][i][j] += fmaf(cz[j], addC[i], addB[i]);
    }

    // ---- partial per-row absmax over this wave's 5 tiles -> pmax
    #pragma unroll
    for (int g = 0; g < 4; ++g) {
        #pragma unroll
        for (int j = 0; j < 4; ++j) {
            float m = fmaxf(fmaxf(fmaxf(fabsf(acc[g][0][j]), fabsf(acc[g][1][j])),
                                  fmaxf(fabsf(acc[g][2][j]), fabsf(acc[g][3][j]))),
                            fabsf(acc[g][4][j]));
            #pragma unroll
            for (int mk = 1; mk < 16; mk <<= 1) m = fmaxf(m, __shfl_xor(m, mk));
            if (lane15 == 0) pmax[tb][hf][g * 16 + hi * 4 + j] = m;
        }
    }
    __syncthreads();   // pmax complete; all h ds_reads done -> smem reusable

    // ---- quantize + LDS byte staging (disjoint col ranges per wave)
    uint8_t* ldsu = smem;
    uint8_t* ldsv = smem + 64 * LROW;
    uint8_t* myt = tb ? ldsv : ldsu;
    #pragma unroll
    for (int g = 0; g < 4; ++g) {
        #pragma unroll
        for (int j = 0; j < 4; ++j) {
            const int row = g * 16 + hi * 4 + j;
            const float mm = fmaxf(fmaxf(pmax[tb][0][row], pmax[tb][1][row]), 1e-20f);
            const float inv = 31.f / mm;
            if (hf == 0 && lane15 == 0)
                *(float*)(myt + row * LROW + 148) = mm * (1.f / 31.f);
            #pragma unroll
            for (int i = 0; i < 5; ++i) {
                const int ccol = (w5 + i) * 16 + lane15 - (tb ? HSTR : 0);
                const uint8_t q = (uint8_t)(uint32_t)(acc[g][i][j] * inv + 32.5f);
                if (ccol < 145)                      // skips pad lanes of tiles 9/19
                    myt[row * LROW + ccol] = q;
            }
        }
    }
    __syncthreads();

    // ---- repack + coalesced copy-out: idx in [0,512): row=idx>>3, chunk c=idx&7
    // chunk c<7: u32s 4c..4c+3 = cols 20c..20c+19; c==7: vals 140-144 + scale
    char* ug = (char*)u + (size_t)n0blk * MROWB;
    char* vg = (char*)v + (size_t)n0blk * MROWB;
    #pragma unroll
    for (int i = 0; i < 2; ++i) {
        const int idx = i * 256 + t;
        const int row = idx >> 3, c = idx & 7;
        if (!full && n0blk + row >= nNodes) continue;
        #pragma unroll
        for (int tab = 0; tab < 2; ++tab) {
            const uint8_t* lr = (tab ? ldsv : ldsu) + row * LROW;
            uint4 o;
            if (c < 7) {
                const uint32_t* wp = (const uint32_t*)(lr + 20 * c);
                const uint32_t b0 = wp[0], b1_ = wp[1], b2 = wp[2], b3 = wp[3], b4 = wp[4];
                o.x = (b0 & 63u) | (((b0 >> 8) & 63u) << 6) | (((b0 >> 16) & 63u) << 12)
                    | (((b0 >> 24) & 63u) << 18) | ((b1_ & 63u) << 24);
                o.y = ((b1_ >> 8) & 63u) | (((b1_ >> 16) & 63u) << 6) | (((b1_ >> 24) & 63u) << 12)
                    | ((b2 & 63u) << 18) | (((b2 >> 8) & 63u) << 24);
                o.z = ((b2 >> 16) & 63u) | (((b2 >> 24) & 63u) << 6) | ((b3 & 63u) << 12)
                    | (((b3 >> 8) & 63u) << 18) | (((b3 >> 16) & 63u) << 24);
                o.w = ((b3 >> 24) & 63u) | ((b4 & 63u) << 6) | (((b4 >> 8) & 63u) << 12)
                    | (((b4 >> 16) & 63u) << 18) | (((b4 >> 24) & 63u) << 24);
            } else {
                const uint32_t w0 = *(const uint32_t*)(lr + 140);
                const uint32_t w1 = *(const uint32_t*)(lr + 144);
                o.x = (w0 & 63u) | (((w0 >> 8) & 63u) << 6) | (((w0 >> 16) & 63u) << 12)
                    | (((w0 >> 24) & 63u) << 18) | ((w1 & 63u) << 24);
                o.y = *(const uint32_t*)(lr + 148);       // f32 scale
                o.z = 0u; o.w = 0u;
            }
            *(uint4*)((tab ? vg : ug) + 16 * idx) = o;
        }
    }
}

// ---------------------------------------------------------------------------
// edge_int6: 4 lanes per edge, 2 edges per group, 32 edges per wave.
//   Lane r reads u32s [8r,8r+8) (2 uint4) of u'[src] and v'[dst] rows.
//   Each u32 = 5 vals at bits 6k; col = 40r + 5*lw + k; w2 zero-padded
//   past col 144 makes scale/pad words contribute exactly 0.
//   Scale = u32 idx 29 = lane 3's 2nd uint4 .y; broadcast via shfl.
// ---------------------------------------------------------------------------
__global__ void __launch_bounds__(256)
edge_int6(const uint32_t* __restrict__ pairs,
          const uint8_t* __restrict__ u, const uint8_t* __restrict__ v,
          const float* __restrict__ w2p, const float* __restrict__ b2,
          float* __restrict__ out, int E)
{
    const int t = threadIdx.x;
    const int lane = t & 63;
    const int r = lane & 3;
    const int grp = lane >> 2;
    const int wid = blockIdx.x * (blockDim.x >> 6) + (t >> 6);
    const int base = wid * 32;
    const int e0 = base + grp, e1 = base + 16 + grp;
    const bool ok0 = e0 < E, ok1 = e1 < E;
    const float bias2 = *b2;

    const uint32_t pr0 = pairs[ok0 ? e0 : 0];
    const uint32_t pr1 = pairs[ok1 ? e1 : 0];

    const uint4* ua = (const uint4*)(u + (pr0 >> 16)     * (uint32_t)MROWB) + 2 * r;
    const uint4* va = (const uint4*)(v + (pr0 & 0xFFFFu) * (uint32_t)MROWB) + 2 * r;
    const uint4* ub = (const uint4*)(u + (pr1 >> 16)     * (uint32_t)MROWB) + 2 * r;
    const uint4* vb = (const uint4*)(v + (pr1 & 0xFFFFu) * (uint32_t)MROWB) + 2 * r;
    const uint4 UA0 = ua[0], UA1 = ua[1];
    const uint4 VA0 = va[0], VA1 = va[1];
    const uint4 UB0 = ub[0], UB1 = ub[1];
    const uint4 VB0 = vb[0], VB1 = vb[1];

    // scales: u32 idx 29 -> lane r=3, 2nd uint4, component y
    const int l3 = lane | 3;
    const float su0 = __shfl(__uint_as_float(UA1.y), l3);
    const float sv0 = __shfl(__uint_as_float(VA1.y), l3);
    const float su1 = __shfl(__uint_as_float(UB1.y), l3);
    const float sv1 = __shfl(__uint_as_float(VB1.y), l3);
    const float off0 = -32.f * (su0 + sv0);
    const float off1 = -32.f * (su1 + sv1);

    uint32_t uw0[8] = {UA0.x, UA0.y, UA0.z, UA0.w, UA1.x, UA1.y, UA1.z, UA1.w};
    uint32_t vw0[8] = {VA0.x, VA0.y, VA0.z, VA0.w, VA1.x, VA1.y, VA1.z, VA1.w};
    uint32_t uw1[8] = {UB0.x, UB0.y, UB0.z, UB0.w, UB1.x, UB1.y, UB1.z, UB1.w};
    uint32_t vw1[8] = {VB0.x, VB0.y, VB0.z, VB0.w, VB1.x, VB1.y, VB1.z, VB1.w};

    const float* w2b = w2p + 40 * r;
    float acc0 = 0.f, acc1 = 0.f;
    #pragma unroll
    for (int lw = 0; lw < 8; ++lw) {
        #pragma unroll
        for (int k = 0; k < 5; ++k) {
            const float w2v = w2b[5 * lw + k];
            const float uf0 = (float)((uw0[lw] >> (6 * k)) & 63u);
            const float vf0 = (float)((vw0[lw] >> (6 * k)) & 63u);
            float tv0 = fmaf(su0, uf0, fmaf(sv0, vf0, off0));
            tv0 = fmaxf(tv0, 0.f);
            acc0 = fmaf(tv0, w2v, acc0);
            const float uf1 = (float)((uw1[lw] >> (6 * k)) & 63u);
            const float vf1 = (float)((vw1[lw] >> (6 * k)) & 63u);
            float tv1 = fmaf(su1, uf1, fmaf(sv1, vf1, off1));
            tv1 = fmaxf(tv1, 0.f);
            acc1 = fmaf(tv1, w2v, acc1);
        }
    }
    acc0 += __shfl_xor(acc0, 1);
    acc0 += __shfl_xor(acc0, 2);
    acc1 += __shfl_xor(acc1, 1);
    acc1 += __shfl_xor(acc1, 2);
    if (r == 0 && ok0) out[e0] = 1.f / (1.f + __expf(-(acc0 + bias2)));
    if (r == 0 && ok1) out[e1] = 1.f / (1.f + __expf(-(acc1 + bias2)));
}

// ---------------------------------------------------------------------------
// fallback_kernel: direct per-edge compute (ws too small or nNodes > 65536)
// ---------------------------------------------------------------------------
__global__ void __launch_bounds__(256)
fallback_kernel(const void* __restrict__ eiv, const float* __restrict__ h,
                const float* __restrict__ cancer, const float* __restrict__ causal,
                const float* __restrict__ W1, const float* __restrict__ b1,
                const float* __restrict__ W2, const float* __restrict__ b2,
                float* __restrict__ out, int E)
{
    const int lane = threadIdx.x & 63;
    const int wpb  = blockDim.x >> 6;
    const int wid  = blockIdx.x * wpb + (threadIdx.x >> 6);
    const int nW   = gridDim.x * wpb;
    const uint32_t* p32 = (const uint32_t*)eiv;
    const uint32_t o = p32[1] | p32[3] | p32[5] | p32[7] | p32[9] | p32[11] | p32[13] | p32[15];
    const int is64 = (o == 0u);
    const long long* e64 = (const long long*)eiv;
    const int*       e32 = (const int*)eiv;
    const float bias2 = *b2;

    for (int e = wid; e < E; e += nW) {
        long long src, dst;
        if (is64) { src = e64[e]; dst = e64[(size_t)E + e]; }
        else      { src = e32[e]; dst = e32[(size_t)E + e]; }
        const float ci = causal[src], cj = causal[dst];
        float acc0 = 0.f, acc1 = 0.f, acc2 = 0.f;
        const int j0 = lane, j1 = lane + 64, j2 = lane + 128;
        for (int k = 0; k < 291; ++k) {
            float f;
            if      (k < 128) f = h[(size_t)src * 128 + k];
            else if (k < 256) f = h[(size_t)dst * 128 + (k - 128)];
            else if (k < 288) f = cancer[k - 256];
            else if (k == 288) f = ci;
            else if (k == 289) f = cj;
            else               f = ci - cj;
            const float* wr = W1 + (size_t)k * HID;
            acc0 = fmaf(f, wr[j0], acc0);
            acc1 = fmaf(f, wr[j1], acc1);
            if (j2 < HID) acc2 = fmaf(f, wr[j2], acc2);
        }
        float partial = fmaxf(acc0 + b1[j0], 0.f) * W2[j0]
                      + fmaxf(acc1 + b1[j1], 0.f) * W2[j1];
        if (j2 < HID) partial += fmaxf(acc2 + b1[j2], 0.f) * W2[j2];
        #pragma unroll
        for (int m = 32; m; m >>= 1) partial += __shfl_xor(partial, m, 64);
        if (lane == 0) out[e] = 1.f / (1.f + __expf(-(partial + bias2)));
    }
}

// ---------------------------------------------------------------------------
extern "C" void kernel_launch(void* const* d_in, const int* in_sizes, int n_in,
                              void* d_out, int out_size, void* d_ws, size_t ws_size,
                              hipStream_t stream)
{
    const float* h      = (const float*)d_in[0];
    const void*  ei     = d_in[1];
    const float* cancer = (const float*)d_in[2];
    const float* causal = (const float*)d_in[3];
    const float* W1     = (const float*)d_in[4];
    const float* b1     = (const float*)d_in[5];
    const float* W2     = (const float*)d_in[6];
    const float* b2     = (const float*)d_in[7];
    float* outp = (float*)d_out;

    const int nNodes = in_sizes[0] / EMBED;
    const int E      = in_sizes[1] / 2;

    // workspace layout
    const size_t WPB_OFF   = 8192;                      // 80 KB -> ends 90112
    const size_t PAIRS_OFF = 98304;
    const size_t pairsB    = ((size_t)E * 4 + 255) & ~(size_t)255;
    const size_t tabB      = (size_t)nNodes * MROWB;    // 6.4 MB each
    const size_t U_OFF     = PAIRS_OFF + pairsB;
    const size_t V_OFF     = (U_OFF + tabB + 255) & ~(size_t)255;
    const size_t need      = V_OFF + tabB;

    char* ws = (char*)d_ws;
    float* b1p  = (float*)(ws + 1024);
    float* wci  = (float*)(ws + 2048);
    float* wcj  = (float*)(ws + 3072);
    float* w2p  = (float*)(ws + 4096);
    short* Wpb  = (short*)(ws + WPB_OFF);

    if (ws_size >= need && nNodes <= 65536) {
        uint32_t* pairs = (uint32_t*)(ws + PAIRS_OFF);
        uint8_t*  u     = (uint8_t*)(ws + U_OFF);
        uint8_t*  v     = (uint8_t*)(ws + V_OFF);

        const int P = (E + 255) / 256;
        prep_fused<<<P + 161, 256, 0, stream>>>(cancer, W1, b1, W2, ei, E, P,
                                                b1p, wci, wcj, w2p, Wpb, pairs);
        proj_mfma<<<(nNodes + 63) / 64, 256, 0, stream>>>(h, Wpb, causal, b1p,
                                                          wci, wcj, u, v, nNodes);
        const int waves  = (E + 31) / 32;
        const int blocks = (waves + 3) / 4;
        edge_int6<<<blocks, 256, 0, stream>>>(pairs, u, v, w2p, b2, outp, E);
    } else {
        fallback_kernel<<<2048, 256, 0, stream>>>(ei, h, cancer, causal, W1, b1, W2, b2,
                                                  outp, E);
    }
}